// Round 4
// baseline (51.289 us; speedup 1.0000x reference)
//
#include <hip/hip_runtime.h>

#define NS 512
#define NB 2
#define DM 512
#define NH 8
#define DH 64
#define NHDH 512
#define ATTN_SIZE (NB * NH * NS * NS)  // 4194304

typedef __attribute__((ext_vector_type(8))) short short8v;
typedef __attribute__((ext_vector_type(4))) float f32x4;
typedef _Float16 h2 __attribute__((ext_vector_type(2)));
typedef unsigned short ushort_t;

__device__ __forceinline__ unsigned short f2bf(float x) {
    unsigned u = __float_as_uint(x);
    u = (u + 0x7FFFu + ((u >> 16) & 1u)) >> 16;   // RNE
    return (unsigned short)u;
}

#if defined(__has_builtin)
#if __has_builtin(__builtin_amdgcn_fdot2)
#define HAVE_FDOT2 1
#endif
#endif

__device__ __forceinline__ float qdot2(unsigned w2, unsigned x2, float acc) {
#ifdef HAVE_FDOT2
    return __builtin_amdgcn_fdot2(__builtin_bit_cast(h2, w2),
                                  __builtin_bit_cast(h2, x2), acc, false);
#else
    h2 a = __builtin_bit_cast(h2, w2);
    h2 b = __builtin_bit_cast(h2, x2);
    return acc + (float)a[0] * (float)b[0] + (float)a[1] * (float)b[1];
#endif
}

__device__ __forceinline__ float dotabs(unsigned w2, unsigned q2, unsigned k2, float acc) {
    h2 s = __builtin_bit_cast(h2, q2) + __builtin_bit_cast(h2, k2);  // v_pk_add_f16
    unsigned a = __builtin_bit_cast(unsigned, s) & 0x7FFF7FFFu;      // |.| both halves
    return qdot2(w2, a, acc);                                        // v_dot2_f32_f16
}

// ---------------------------------------------------------------------------
// Pass 0: query f32 -> bf16; Wq/Wk f32 -> bf16 TRANSPOSED (Wt[col][k]).
// ---------------------------------------------------------------------------
__global__ __launch_bounds__(256) void convert_kernel(
    const float* __restrict__ query,
    const float* __restrict__ Wq, const float* __restrict__ Wk,
    ushort_t* __restrict__ Xb,
    ushort_t* __restrict__ Wqt, ushort_t* __restrict__ Wkt)
{
    __shared__ __align__(16) ushort_t Ts[64][72];
    const int tid = threadIdx.x;
    const int blk = blockIdx.x;

    if (blk < 128) {
        const int base = blk * 4096 + tid * 16;
        float4 v0 = *(const float4*)(query + base);
        float4 v1 = *(const float4*)(query + base + 4);
        float4 v2 = *(const float4*)(query + base + 8);
        float4 v3 = *(const float4*)(query + base + 12);
        union { ushort_t us[8]; uint4 v; } p0, p1;
        p0.us[0] = f2bf(v0.x); p0.us[1] = f2bf(v0.y); p0.us[2] = f2bf(v0.z); p0.us[3] = f2bf(v0.w);
        p0.us[4] = f2bf(v1.x); p0.us[5] = f2bf(v1.y); p0.us[6] = f2bf(v1.z); p0.us[7] = f2bf(v1.w);
        p1.us[0] = f2bf(v2.x); p1.us[1] = f2bf(v2.y); p1.us[2] = f2bf(v2.z); p1.us[3] = f2bf(v2.w);
        p1.us[4] = f2bf(v3.x); p1.us[5] = f2bf(v3.y); p1.us[6] = f2bf(v3.z); p1.us[7] = f2bf(v3.w);
        *(uint4*)(Xb + base) = p0.v;
        *(uint4*)(Xb + base + 8) = p1.v;
        return;
    }

    const float* __restrict__ W = (blk < 192) ? Wq : Wk;
    ushort_t* __restrict__ Wt = (blk < 192) ? Wqt : Wkt;
    const int t  = (blk - 128) & 63;
    const int tr = t >> 3;   // k-tile
    const int tc = t & 7;    // col-tile

    {
        const int r  = tid >> 2;
        const int cq = tid & 3;
        const float* src = W + (size_t)(tr * 64 + r) * NHDH + tc * 64 + cq * 16;
        #pragma unroll
        for (int v = 0; v < 4; ++v) {
            float4 a = *(const float4*)(src + v * 4);
            Ts[cq * 16 + v * 4 + 0][r] = f2bf(a.x);
            Ts[cq * 16 + v * 4 + 1][r] = f2bf(a.y);
            Ts[cq * 16 + v * 4 + 2][r] = f2bf(a.z);
            Ts[cq * 16 + v * 4 + 3][r] = f2bf(a.w);
        }
    }
    __syncthreads();
    {
        const int c  = tid >> 2;
        const int kq = tid & 3;
        uint4 o0 = *(const uint4*)&Ts[c][kq * 16];
        uint4 o1 = *(const uint4*)&Ts[c][kq * 16 + 8];
        ushort_t* dst = Wt + (size_t)(tc * 64 + c) * DM + tr * 64 + kq * 16;
        *(uint4*)(dst) = o0;
        *(uint4*)(dst + 8) = o1;
    }
}

// ---------------------------------------------------------------------------
// Pass 1: MFMA bf16 GEMM -> [b,h,ns,dh]. Epilogue writes f16 copies for the
// attn kernel (qh/kh) and the f32 k_out output (bz==1 only).
// ---------------------------------------------------------------------------
__global__ __launch_bounds__(256) void proj_mfma(
    const ushort_t* __restrict__ Xb,
    const ushort_t* __restrict__ Wqt, const ushort_t* __restrict__ Wkt,
    const float* __restrict__ bq, const float* __restrict__ bk,
    ushort_t* __restrict__ qh, ushort_t* __restrict__ kh,
    float* __restrict__ kout)
{
    const int h  = blockIdx.x;
    const int by = blockIdx.y;
    const int bz = blockIdx.z;
    const ushort_t* __restrict__ Wt = bz ? Wkt : Wqt;
    const float* __restrict__ bia = bz ? bk : bq;
    ushort_t* __restrict__ hout = bz ? kh : qh;

    __shared__ __align__(16) ushort_t As[64][136];
    __shared__ __align__(16) ushort_t Bs[64][136];

    const int tid  = threadIdx.x;
    const int lane = tid & 63;
    const int w    = __builtin_amdgcn_readfirstlane(tid >> 6);
    const int wr   = w >> 1, wc = w & 1;
    const int l15  = lane & 15, l4 = lane >> 4;

    uint4 ra[4], rb[4];
    #pragma unroll
    for (int i = 0; i < 4; ++i) {
        int s = i * 256 + tid;
        int row = s >> 4, q = s & 15;
        ra[i] = *(const uint4*)(Xb + (size_t)(by * 64 + row) * DM + q * 8);
        rb[i] = *(const uint4*)(Wt + (size_t)(h * 64 + row) * DM + q * 8);
    }

    f32x4 acc[2][2];
    #pragma unroll
    for (int f = 0; f < 2; ++f)
        #pragma unroll
        for (int g = 0; g < 2; ++g) acc[f][g] = (f32x4){0.f, 0.f, 0.f, 0.f};

    for (int kc = 0; kc < 4; ++kc) {
        __syncthreads();
        #pragma unroll
        for (int i = 0; i < 4; ++i) {
            int s = i * 256 + tid;
            int row = s >> 4, q = s & 15;
            *(uint4*)&As[row][q * 8] = ra[i];
            *(uint4*)&Bs[row][q * 8] = rb[i];
        }
        __syncthreads();
        if (kc < 3) {
            #pragma unroll
            for (int i = 0; i < 4; ++i) {
                int s = i * 256 + tid;
                int row = s >> 4, q = s & 15;
                ra[i] = *(const uint4*)(Xb + (size_t)(by * 64 + row) * DM + (kc + 1) * 128 + q * 8);
                rb[i] = *(const uint4*)(Wt + (size_t)(h * 64 + row) * DM + (kc + 1) * 128 + q * 8);
            }
        }
        #pragma unroll
        for (int ks = 0; ks < 4; ++ks) {
            short8v a0 = *(const short8v*)&As[wr * 32 + l15     ][ks * 32 + l4 * 8];
            short8v a1 = *(const short8v*)&As[wr * 32 + 16 + l15][ks * 32 + l4 * 8];
            short8v b0 = *(const short8v*)&Bs[wc * 32 + l15     ][ks * 32 + l4 * 8];
            short8v b1 = *(const short8v*)&Bs[wc * 32 + 16 + l15][ks * 32 + l4 * 8];
            acc[0][0] = __builtin_amdgcn_mfma_f32_16x16x32_bf16(a0, b0, acc[0][0], 0, 0, 0);
            acc[0][1] = __builtin_amdgcn_mfma_f32_16x16x32_bf16(a0, b1, acc[0][1], 0, 0, 0);
            acc[1][0] = __builtin_amdgcn_mfma_f32_16x16x32_bf16(a1, b0, acc[1][0], 0, 0, 0);
            acc[1][1] = __builtin_amdgcn_mfma_f32_16x16x32_bf16(a1, b1, acc[1][1], 0, 0, 0);
        }
    }

    const float bias0 = bia[h * 64 + wc * 32 + l15];
    const float bias1 = bia[h * 64 + wc * 32 + 16 + l15];
    #pragma unroll
    for (int f = 0; f < 2; ++f)
        #pragma unroll
        for (int g = 0; g < 2; ++g) {
            float bg = g ? bias1 : bias0;
            #pragma unroll
            for (int j = 0; j < 4; ++j) {
                int rt = wr * 32 + f * 16 + l4 * 4 + j;
                int ct = wc * 32 + g * 16 + l15;
                int rg = by * 64 + rt;
                int ns_ = rg >> 1, b_ = rg & 1;
                size_t idx = ((size_t)(b_ * NH + h) * NS + ns_) * DH + ct;
                float vv = acc[f][g][j] + bg;
                if (bz) kout[idx] = vv;
                _Float16 hv = (_Float16)vv;
                hout[idx] = __builtin_bit_cast(ushort_t, hv);
            }
        }
}

// ---------------------------------------------------------------------------
// Pass 2: attn[b,h,q,k] = 0.505*(Qd[q]+Kd[k]) + 0.495*sum_e w[e]*|q[e]+k[e]|
// 512 blocks = (bh:16) x (qt:32 of 16 q-rows). 4 waves: (qhalf, khalf).
// Wave = 8 q-rows x 256 k-cols; lane owns 4 consecutive k-rows in registers
// (f16, loaded direct from global; zero LDS for K). Q streamed from a 2KB
// LDS tile (8 uniform b128 per row). w in SGPRs. Core: 3 insts / 2 elems.
// ---------------------------------------------------------------------------
__global__ __launch_bounds__(256, 2) void attn_kernel(
    const ushort_t* __restrict__ qh,   // [bh][ns][dh] f16
    const ushort_t* __restrict__ kh,   // [bh][ns][dh] f16
    const float* __restrict__ w,       // [8][64] f32
    float* __restrict__ attn)          // [b,h,q,k]
{
    __shared__ __align__(16) ushort_t Qs[16][64];  // 2 KB

    const int tid   = threadIdx.x;
    const int lane  = tid & 63;
    const int wv    = tid >> 6;
    const int qhalf = wv >> 1;
    const int khalf = wv & 1;
    const int bidx  = blockIdx.x;
    const int bh    = bidx >> 5;     // 0..15
    const int qt    = bidx & 31;     // 16-row q tile
    const int h     = bh & 7;

    // ---- K rows -> registers (4 rows x 64 f16 = 128 VGPRs) ----
    const int kc0 = khalf * 256 + lane * 4;
    const ushort_t* kb = kh + (size_t)bh * NS * DH + (size_t)kc0 * DH;
    __align__(16) unsigned kr[4][32];
    #pragma unroll
    for (int j = 0; j < 4; ++j)
        #pragma unroll
        for (int i = 0; i < 8; ++i)
            *(uint4*)&kr[j][i * 4] = *(const uint4*)(kb + j * DH + i * 8);

    // ---- Q tile -> LDS (16 rows x 128 B) ----
    if (tid < 128) {
        ((uint4*)&Qs[0][0])[tid] =
            *((const uint4*)(qh + (size_t)bh * NS * DH + (size_t)qt * 16 * DH) + tid);
    }

    // ---- scoring weights -> f16 pairs in SGPRs ----
    unsigned wp[32];
    const float* wrow = w + h * DH;
    #pragma unroll
    for (int i = 0; i < 16; ++i) {
        float4 v = *(const float4*)(wrow + i * 4);
        _Float16 a = (_Float16)v.x, b = (_Float16)v.y, c = (_Float16)v.z, d = (_Float16)v.w;
        unsigned lo = (unsigned)__builtin_bit_cast(ushort_t, a) |
                      ((unsigned)__builtin_bit_cast(ushort_t, b) << 16);
        unsigned hi = (unsigned)__builtin_bit_cast(ushort_t, c) |
                      ((unsigned)__builtin_bit_cast(ushort_t, d) << 16);
        wp[2 * i]     = __builtin_amdgcn_readfirstlane(lo);
        wp[2 * i + 1] = __builtin_amdgcn_readfirstlane(hi);
    }

    // ---- Kdot per owned k-row ----
    float kd0 = 0.f, kd1 = 0.f, kd2 = 0.f, kd3 = 0.f;
    #pragma unroll
    for (int p = 0; p < 32; ++p) {
        kd0 = qdot2(wp[p], kr[0][p], kd0);
        kd1 = qdot2(wp[p], kr[1][p], kd1);
        kd2 = qdot2(wp[p], kr[2][p], kd2);
        kd3 = qdot2(wp[p], kr[3][p], kd3);
    }

    __syncthreads();

    float* obase = attn + (size_t)bh * NS * NS + (size_t)(qt * 16 + qhalf * 8) * NS + kc0;

    #pragma unroll 2
    for (int r = 0; r < 8; ++r) {
        const int row = qhalf * 8 + r;
        __align__(16) unsigned q2a[32];
        #pragma unroll
        for (int i = 0; i < 8; ++i)
            *(uint4*)&q2a[i * 4] = *((const uint4*)&Qs[row][0] + i);

        float qd = 0.f;
        #pragma unroll
        for (int p = 0; p < 32; ++p) qd = qdot2(wp[p], q2a[p], qd);

        float a0 = 0.f, a1 = 0.f, a2 = 0.f, a3 = 0.f;
        #pragma unroll
        for (int p = 0; p < 32; ++p) {
            const unsigned q2 = q2a[p], w2 = wp[p];
            a0 = dotabs(w2, q2, kr[0][p], a0);
            a1 = dotabs(w2, q2, kr[1][p], a1);
            a2 = dotabs(w2, q2, kr[2][p], a2);
            a3 = dotabs(w2, q2, kr[3][p], a3);
        }

        float4 o;
        o.x = fmaf(0.495f, a0, 0.505f * (qd + kd0));
        o.y = fmaf(0.495f, a1, 0.505f * (qd + kd1));
        o.z = fmaf(0.495f, a2, 0.505f * (qd + kd2));
        o.w = fmaf(0.495f, a3, 0.505f * (qd + kd3));
        *(float4*)(obase + r * NS) = o;
    }
}

extern "C" void kernel_launch(void* const* d_in, const int* in_sizes, int n_in,
                              void* d_out, int out_size, void* d_ws, size_t ws_size,
                              hipStream_t stream) {
    const float* query = (const float*)d_in[0];
    const float* Wq    = (const float*)d_in[1];
    const float* bq    = (const float*)d_in[2];
    const float* Wk    = (const float*)d_in[3];
    const float* bk    = (const float*)d_in[4];
    const float* w     = (const float*)d_in[5];

    float* attn = (float*)d_out;
    float* kout = (float*)d_out + ATTN_SIZE;     // k-proj f32 == output 2

    char* ws = (char*)d_ws;
    ushort_t* Xb  = (ushort_t*)(ws);                       // 1 MB bf16 query
    ushort_t* Wqt = (ushort_t*)(ws + (1u << 20));          // 0.5 MB bf16 Wq^T
    ushort_t* Wkt = (ushort_t*)(ws + (1u << 20) + DM * NHDH * 2);
    ushort_t* qh  = (ushort_t*)(ws + (2u << 20));          // 1 MB f16 q-proj
    ushort_t* kh  = (ushort_t*)(ws + (3u << 20));          // 1 MB f16 k-proj

    convert_kernel<<<256, 256, 0, stream>>>(query, Wq, Wk, Xb, Wqt, Wkt);
    proj_mfma<<<dim3(NH, 16, 2), 256, 0, stream>>>(Xb, Wqt, Wkt, bq, bk, qh, kh, kout);
    attn_kernel<<<512, 256, 0, stream>>>(qh, kh, w, attn);
}